// Round 3
// baseline (246.232 us; speedup 1.0000x reference)
//
#include <hip/hip_runtime.h>
#include <stdint.h>

#define BATCH 32
#define TLEN  1024
#define DIN   512
#define DOUT  512
#define KW    5
#define TOUT  1020          // TLEN - KW + 1
#define KDIM  (DIN * KW)    // 2560

#define BM 256
#define BN 256
#define BK 64
#define NT (KDIM / BK)      // 40 K-tiles
#define ATILE_E (BM * BK)   // 16384 elems = 32 KB per A buffer

typedef __attribute__((ext_vector_type(8))) short bf16x8;
typedef __attribute__((ext_vector_type(4))) float f32x4;

__device__ __forceinline__ uint16_t f2bf(float f) {
    uint32_t u = __float_as_uint(f);
    uint32_t r = u + 0x7FFFu + ((u >> 16) & 1u);   // RNE to bf16
    return (uint16_t)(r >> 16);
}

// Grid-strided fat-block convert+pack.
__global__ void __launch_bounds__(256)
convert_pack(const float4* __restrict__ x, uint4* __restrict__ xb,
             const float* __restrict__ w, uint16_t* __restrict__ wb) {
    const int tid = threadIdx.x;
    for (int u = blockIdx.x; u < 8192; u += 1024) {
        int idx = u * 256 + tid;
        float4 a = x[2 * idx];
        float4 b = x[2 * idx + 1];
        uint4 v;
        v.x = (uint32_t)f2bf(a.x) | ((uint32_t)f2bf(a.y) << 16);
        v.y = (uint32_t)f2bf(a.z) | ((uint32_t)f2bf(a.w) << 16);
        v.z = (uint32_t)f2bf(b.x) | ((uint32_t)f2bf(b.y) << 16);
        v.w = (uint32_t)f2bf(b.z) | ((uint32_t)f2bf(b.w) << 16);
        xb[idx] = v;
    }
    __shared__ float4 lw4[320];
    float* lw = (float*)lw4;
    const int o = blockIdx.x >> 1;
    const int h = blockIdx.x & 1;
    const float4* src = (const float4*)(w + (size_t)o * KDIM + h * 1280);
    #pragma unroll
    for (int j = tid; j < 320; j += 256) lw4[j] = src[j];
    __syncthreads();
    #pragma unroll
    for (int k = 0; k < KW; ++k)
        wb[(size_t)o * KDIM + k * DIN + h * 256 + tid] = f2bf(lw[tid * 5 + k]);
}

// ---------------------------------------------------------------------------
// GEMM: C[m=(b,t), n=o] = sum_k xflat[b,t*512+k] * Wb[n][k]
//
// A (x, im2col) : LDS, double-buffered 64 KB, XOR-chunk swizzle (0 conflicts).
// B (weights)   : GLOBAL->REG direct (wb = 2.6 MB, L2-resident; no reuse
//                 inside a block -> LDS staging for B was pure overhead).
// 8 waves (2M x 4N), per-wave out 128x64, acc[8][4] (128 AGPR).
//
// K-tile = 4 slots, m-major quadrants: q00(m0n0) q01(m0n1) q11(m1n1) q10(m1n0)
//   afA = A-H0(kt) ds-read @ kt-1.q11, used q00,q01;   (H = wave-m-half)
//   afB = A-H1(kt) ds-read @ kt.q01,   used q11,q10;
//   bf1 = B-H1(kt) glb     @ kt.q00,   used q01,q11;   (H = wave-n-half)
//   bf0 = B-H0(kt+1) glb   @ kt.q10(post-MFMA, WAR-safe), used next q00,q10.
// Stages (A halves of kt+2, same-parity buffer):
//   A-H0(kt+2) @ kt.q01 (region's readers drained by kt.q00 lgkm + barrier)
//   A-H1(kt+2) @ kt.q10 (readers drained by kt.q11 lgkm + q11-end barrier)
// vmcnt ledger (loads; stage half = 2, B batch = 4), steady state:
//   entering q00: [stgA-H0(kt+1) 2][B-H0(kt) 4][stgA-H1(kt+1) 2]
//   q00 after issuing B-H1(kt): 12 outstanding -> vmcnt(6)
//        proves B-H0(kt) (MFMA) + stgA-H0(kt+1) (ds @ kt.q11)
//   q01 after issuing stgA-H0(kt+2): vmcnt(2)
//        proves B-H1(kt) (MFMA) + stgA-H1(kt) (ds afB this slot; all-waves
//        visibility via q01-end barrier for kt+1's ds -> see below)
// lgkm: q00 lgkmcnt(0) (afA issued 2 slots ago - free); q11 lgkmcnt(8)
//        (drains afB(kt), leaves afA(kt+1) in flight). Never a hot drain.
// Barriers: 3 per K-tile (q00,q01,q11 ends). q10-end barrier is redundant:
//   first LDS op after it is kt+1.q01's, behind kt+1.q00-end barrier.
// Cross-wave staging visibility: each region's stage is proven by every
//   wave's counted vmcnt BEFORE a barrier that precedes any ds_read of it
//   (A-H0: q00's vmcnt(6)+barrier, 6 slots ahead of its read;
//    A-H1: q01's vmcnt(2)+q01-end barrier, 4 slots ahead).
// ---------------------------------------------------------------------------

#define SB() __builtin_amdgcn_sched_barrier(0)
#define BAR() do { __builtin_amdgcn_s_barrier(); SB(); } while (0)
#define WAITVM(N) do { asm volatile("s_waitcnt vmcnt(" #N ")" ::: "memory"); SB(); } while (0)
#define WAITLG(N) do { asm volatile("s_waitcnt lgkmcnt(" #N ")" ::: "memory"); SB(); } while (0)

#define STAGE_A(BUF_, MH_, KT_) do {                                           \
    _Pragma("unroll")                                                          \
    for (int ii = 0; ii < 2; ++ii) {                                           \
        const uint16_t* gp_ = xrow + ab + (MH_) * 32768 + ii * 65536 + (KT_) * 64; \
        const uint16_t* lp_ = As_ + (BUF_) * ATILE_E + (MH_) * 8192 + ii * 4096 + w * 512; \
        __builtin_amdgcn_global_load_lds(                                      \
            (const __attribute__((address_space(1))) void*)gp_,                \
            (__attribute__((address_space(3))) void*)lp_, 16, 0, 0);           \
    }                                                                          \
} while (0)

#define DS_AFA(SRC_) do {                                                      \
    _Pragma("unroll")                                                          \
    for (int mi = 0; mi < 4; ++mi) {                                           \
        afA[mi][0] = *(const bf16x8*)&As_[(SRC_) * ATILE_E + mi * 1024 + ae0]; \
        afA[mi][1] = *(const bf16x8*)&As_[(SRC_) * ATILE_E + mi * 1024 + ae1]; \
    }                                                                          \
} while (0)

#define DS_AFB(SRC_) do {                                                      \
    _Pragma("unroll")                                                          \
    for (int mi = 0; mi < 4; ++mi) {                                           \
        afB[mi][0] = *(const bf16x8*)&As_[(SRC_) * ATILE_E + 8192 + mi * 1024 + ae0]; \
        afB[mi][1] = *(const bf16x8*)&As_[(SRC_) * ATILE_E + 8192 + mi * 1024 + ae1]; \
    }                                                                          \
} while (0)

#define GLB_B0(KT_) do {                                                       \
    bf0[0][0] = *(const bf16x8*)(wrow + bo00 + (KT_) * 64);                    \
    bf0[0][1] = *(const bf16x8*)(wrow + bo00 + (KT_) * 64 + 32);               \
    bf0[1][0] = *(const bf16x8*)(wrow + bo01 + (KT_) * 64);                    \
    bf0[1][1] = *(const bf16x8*)(wrow + bo01 + (KT_) * 64 + 32);               \
} while (0)

#define GLB_B1(KT_) do {                                                       \
    bf1[0][0] = *(const bf16x8*)(wrow + bo10 + (KT_) * 64);                    \
    bf1[0][1] = *(const bf16x8*)(wrow + bo10 + (KT_) * 64 + 32);               \
    bf1[1][0] = *(const bf16x8*)(wrow + bo11 + (KT_) * 64);                    \
    bf1[1][1] = *(const bf16x8*)(wrow + bo11 + (KT_) * 64 + 32);               \
} while (0)

#define MMA(MH_, NH_, AF_, BF_) do {                                           \
    __builtin_amdgcn_s_setprio(1);                                             \
    _Pragma("unroll")                                                          \
    for (int h2 = 0; h2 < 2; ++h2)                                             \
        _Pragma("unroll")                                                      \
        for (int mi = 0; mi < 4; ++mi)                                         \
            _Pragma("unroll")                                                  \
            for (int ni = 0; ni < 2; ++ni)                                     \
                acc[(MH_) * 4 + mi][(NH_) * 2 + ni] =                          \
                    __builtin_amdgcn_mfma_f32_16x16x32_bf16(                   \
                        AF_[mi][h2], BF_[ni][h2],                              \
                        acc[(MH_) * 4 + mi][(NH_) * 2 + ni], 0, 0, 0);         \
    __builtin_amdgcn_s_setprio(0);                                             \
} while (0)

// Steady K-tile (kt <= 37: kt+1 and kt+2 both valid)
#define TILE_STEADY(BUF_, KT_)                                                 \
    /* q00 */                                                                  \
    GLB_B1(KT_);                                                               \
    WAITVM(6); WAITLG(0);                                                      \
    MMA(0, 0, afA, bf0);                                                       \
    BAR();                                                                     \
    /* q01 */                                                                  \
    STAGE_A(BUF_, 0, (KT_) + 2);                                               \
    WAITVM(2);                                                                 \
    DS_AFB(BUF_);                                                              \
    MMA(0, 1, afA, bf1);                                                       \
    BAR();                                                                     \
    /* q11 */                                                                  \
    DS_AFA(1 - (BUF_));                                                        \
    WAITLG(8);                                                                 \
    MMA(1, 1, afB, bf1);                                                       \
    BAR();                                                                     \
    /* q10 */                                                                  \
    STAGE_A(BUF_, 1, (KT_) + 2);                                               \
    MMA(1, 0, afB, bf0);                                                       \
    GLB_B0((KT_) + 1);                                                         \
    SB();

__global__ void __launch_bounds__(512, 2)
tdnn_gemm(const uint16_t* __restrict__ xb,
          const uint16_t* __restrict__ wb,
          const float* __restrict__ bias,
          float* __restrict__ out) {
    __shared__ uint16_t As_[2 * ATILE_E];   // 64 KB, double-buffered A only

    // XCD-aware swizzle: 256 blocks, 32/XCD; the 2 N-tiles of an M-tile are
    // adjacent on the same XCD (A-panel L2 reuse).
    const int j  = blockIdx.x;
    const int g  = (j & 7) * 32 + (j >> 3);
    const int mt = g >> 1;
    const int nt = g & 1;
    const int b  = mt >> 2;
    const int t0 = (mt & 3) * BM;
    const int n0 = nt * BN;

    const int tid  = threadIdx.x;
    const int lane = tid & 63;
    const int w    = tid >> 6;             // wave 0..7
    const int wm   = w >> 2;               // 0..1 (M)
    const int wn   = w & 3;                // 0..3 (N)
    const int ml   = lane & 15;
    const int kg   = lane >> 4;            // 16B chunk group in K=32

    const uint16_t* xrow = xb + (size_t)b * TLEN * DIN + (size_t)t0 * DIN;
    const uint16_t* wrow = wb + (size_t)n0 * KDIM;

    // A staging per-lane element offset: c = ii*512 + w*64 + lane;
    // lds row rh = c>>3 (per half), global row gr = ii*128 + mh*64 + rh0,
    // chunk g = (c&7) ^ (rh&7)  (XOR swizzle, verified 0 conflicts).
    const int rh0 = (w * 64 + lane) >> 3;                       // 0..63
    const int gsw = (lane & 7) ^ ((w * 8 + (lane >> 3)) & 7);
    const int ab  = rh0 * DIN + gsw * 8;

    // A ds-read element offsets (within buf/half): row rh = wm*64+mi*16+ml,
    // elem = rh*64 + ((h2*4+kg)^(ml&7))*8 ; mi*1024 added as immediate.
    const int ae0 = wm * 4096 + ml * 64 + ((kg)     ^ (ml & 7)) * 8;
    const int ae1 = wm * 4096 + ml * 64 + ((4 + kg) ^ (ml & 7)) * 8;

    // B global element offsets: row n = wn*64 + half*32 + ni*16 + ml.
    const int bo00 = (wn * 64 +  0 + ml) * KDIM + kg * 8;
    const int bo01 = (wn * 64 + 16 + ml) * KDIM + kg * 8;
    const int bo10 = (wn * 64 + 32 + ml) * KDIM + kg * 8;
    const int bo11 = (wn * 64 + 48 + ml) * KDIM + kg * 8;

    f32x4 acc[8][4] = {};
    bf16x8 afA[4][2], afB[4][2];
    bf16x8 bf0[2][2], bf1[2][2];

    // Prologue: mimic steady-state queue. Issue order:
    //  [A-H0(0) 2][A-H1(0) 2] [A-H0(1) 2][B-H0(0) 4][A-H1(1) 2]
    //  vmcnt(8) proves kt0's A fully; leaves exactly the steady queue.
    STAGE_A(0, 0, 0);
    STAGE_A(0, 1, 0);
    STAGE_A(1, 0, 1);
    GLB_B0(0);
    STAGE_A(1, 1, 1);
    WAITVM(8);
    BAR();
    DS_AFA(0);                 // afA <- A-H0(0)  (normally @ kt-1.q11)

    for (int kt = 0; kt < 38; kt += 2) {
        TILE_STEADY(0, kt)
        TILE_STEADY(1, kt + 1)
    }

    // kt = 38 (buf0): no kt+2 stages.
    GLB_B1(38);
    WAITVM(6); WAITLG(0);
    MMA(0, 0, afA, bf0);
    BAR();
    WAITVM(0);
    DS_AFB(0);
    MMA(0, 1, afA, bf1);
    BAR();
    DS_AFA(1);
    WAITLG(8);
    MMA(1, 1, afB, bf1);
    BAR();
    MMA(1, 0, afB, bf0);
    GLB_B0(39);
    SB();

    // kt = 39 (buf1): last tile.
    GLB_B1(39);
    WAITVM(4); WAITLG(0);
    MMA(0, 0, afA, bf0);
    BAR();
    WAITVM(0);
    DS_AFB(1);
    MMA(0, 1, afA, bf1);
    BAR();
    WAITLG(0);
    MMA(1, 1, afB, bf1);
    MMA(1, 0, afB, bf0);

    // Epilogue: D map col=lane&15 -> o, row=(lane>>4)*4+r -> t; float4 stores.
    const int rq = (lane >> 4) * 4;
    #pragma unroll
    for (int nf = 0; nf < 4; ++nf) {
        const int o = n0 + wn * 64 + (nf >> 1) * 32 + (nf & 1) * 16 + ml;
        const float bv = bias[o];
        float* orow = out + ((size_t)b * DOUT + o) * TOUT;
        #pragma unroll
        for (int mf = 0; mf < 8; ++mf) {
            const int tb_ = t0 + wm * 128 + (mf >> 2) * 64 + (mf & 3) * 16 + rq;
            if (tb_ + 3 < TOUT) {
                float4 s;
                s.x = fmaxf(acc[mf][nf][0] + bv, 0.0f);
                s.y = fmaxf(acc[mf][nf][1] + bv, 0.0f);
                s.z = fmaxf(acc[mf][nf][2] + bv, 0.0f);
                s.w = fmaxf(acc[mf][nf][3] + bv, 0.0f);
                *(float4*)(orow + tb_) = s;
            }
        }
    }
}

extern "C" void kernel_launch(void* const* d_in, const int* in_sizes, int n_in,
                              void* d_out, int out_size, void* d_ws, size_t ws_size,
                              hipStream_t stream) {
    const float* x    = (const float*)d_in[0];
    const float* wgt  = (const float*)d_in[1];
    const float* bias = (const float*)d_in[2];
    float* out = (float*)d_out;

    uint16_t* xb = (uint16_t*)d_ws;                                   // 33.55 MB
    uint16_t* wb = (uint16_t*)((char*)d_ws + (size_t)BATCH * TLEN * DIN * 2);

    convert_pack<<<1024, 256, 0, stream>>>((const float4*)x, (uint4*)xb, wgt, wb);
    tdnn_gemm<<<256, 512, 0, stream>>>(xb, wb, bias, out);
}

// Round 4
// 198.399 us; speedup vs baseline: 1.2411x; 1.2411x over previous
//
#include <hip/hip_runtime.h>
#include <stdint.h>

#define BATCH 32
#define TLEN  1024
#define DIN   512
#define DOUT  512
#define KW    5
#define TOUT  1020          // TLEN - KW + 1
#define KDIM  (DIN * KW)    // 2560

// 256x256 tile, 8-phase counted-vmcnt schedule (T2+T3+T4+T5)
#define BM 256
#define BN 256
#define BK 64
#define NT (KDIM / BK)      // 40 K-tiles
#define TILE_E (BM * BK)    // 16384 bf16 elems per buffer per matrix (32 KB)

typedef __attribute__((ext_vector_type(8))) short bf16x8;
typedef __attribute__((ext_vector_type(4))) float f32x4;

__device__ __forceinline__ uint16_t f2bf(float f) {
    uint32_t u = __float_as_uint(f);
    uint32_t r = u + 0x7FFFu + ((u >> 16) & 1u);   // RNE to bf16
    return (uint16_t)(r >> 16);
}

// Grid-strided fat-block convert+pack.
__global__ void __launch_bounds__(256)
convert_pack(const float4* __restrict__ x, uint4* __restrict__ xb,
             const float* __restrict__ w, uint16_t* __restrict__ wb) {
    const int tid = threadIdx.x;
    for (int u = blockIdx.x; u < 8192; u += 1024) {
        int idx = u * 256 + tid;
        float4 a = x[2 * idx];
        float4 b = x[2 * idx + 1];
        uint4 v;
        v.x = (uint32_t)f2bf(a.x) | ((uint32_t)f2bf(a.y) << 16);
        v.y = (uint32_t)f2bf(a.z) | ((uint32_t)f2bf(a.w) << 16);
        v.z = (uint32_t)f2bf(b.x) | ((uint32_t)f2bf(b.y) << 16);
        v.w = (uint32_t)f2bf(b.z) | ((uint32_t)f2bf(b.w) << 16);
        xb[idx] = v;
    }
    __shared__ float4 lw4[320];
    float* lw = (float*)lw4;
    const int o = blockIdx.x >> 1;
    const int h = blockIdx.x & 1;
    const float4* src = (const float4*)(w + (size_t)o * KDIM + h * 1280);
    #pragma unroll
    for (int j = tid; j < 320; j += 256) lw4[j] = src[j];
    __syncthreads();
    #pragma unroll
    for (int k = 0; k < KW; ++k)
        wb[(size_t)o * KDIM + k * DIN + h * 256 + tid] = f2bf(lw[tid * 5 + k]);
}

// ---------------------------------------------------------------------------
// GEMM: C[m=(b,t), n=o] = sum_k xflat[b, t*512+k] * Wb[n][k]   (im2col view)
//
// Round-2 structure (A and B both LDS-staged, double-buffered 128 KiB),
// with the explicit lgkmcnt(0) drains REMOVED: ds_reads are plain C++ loads,
// so the compiler emits fine-grained lgkmcnt before each dependent MFMA and
// the first MFMA overlaps the tail of the read burst. Counted vmcnt waits
// (which the compiler CANNOT derive: gload_lds has no register result) stay,
// pinned with sched_barrier.
//
// Safety ledger (unchanged from round 2):
//  - stage of region R is >=1 barrier after every wave's ds_read ISSUE of R
//    (LDS pipeline is in-order: issued-before-barrier reads see old data).
//  - data availability: every staged region is proven by a counted vmcnt +
//    barrier >=2 phases before any ds_read of it (vmcnt(6) at p3 proves
//    through (kt+1).B-H0; prologue vmcnt(6) proves kt0 fully).
// ---------------------------------------------------------------------------

#define SB() __builtin_amdgcn_sched_barrier(0)
#define BAR() __builtin_amdgcn_s_barrier()

#define STAGE_A(buf_, mh_, kt_) do {                                           \
    _Pragma("unroll")                                                          \
    for (int ii = 0; ii < 2; ++ii) {                                          \
        int c_  = ii * 512 + w * 64 + lane;                                   \
        int rh_ = c_ >> 3;                                                    \
        int g_  = (c_ & 7) ^ (rh_ & 7);                                       \
        int gr_ = ((rh_ >> 6) << 7) + (mh_) * 64 + (rh_ & 63);                \
        const uint16_t* gp_ = xrow + (size_t)gr_ * DIN + (kt_) * BK + g_ * 8; \
        const uint16_t* lp_ = As_ + (buf_) * TILE_E + (mh_) * 8192 + (ii * 512 + w * 64) * 8; \
        __builtin_amdgcn_global_load_lds(                                     \
            (const __attribute__((address_space(1))) void*)gp_,               \
            (__attribute__((address_space(3))) void*)lp_, 16, 0, 0);          \
    }                                                                          \
} while (0)

#define STAGE_B(buf_, nh_, kt_) do {                                           \
    _Pragma("unroll")                                                          \
    for (int ii = 0; ii < 2; ++ii) {                                          \
        int c_  = ii * 512 + w * 64 + lane;                                   \
        int rh_ = c_ >> 3;                                                    \
        int g_  = (c_ & 7) ^ (rh_ & 7);                                       \
        int gr_ = ((rh_ >> 5) << 6) + (nh_) * 32 + (rh_ & 31);                \
        const uint16_t* gp_ = wrow + (size_t)gr_ * KDIM + (kt_) * BK + g_ * 8;\
        const uint16_t* lp_ = Bs_ + (buf_) * TILE_E + (nh_) * 8192 + (ii * 512 + w * 64) * 8; \
        __builtin_amdgcn_global_load_lds(                                     \
            (const __attribute__((address_space(1))) void*)gp_,               \
            (__attribute__((address_space(3))) void*)lp_, 16, 0, 0);          \
    }                                                                          \
} while (0)

// A lds row = mh*128 + wm*64 + q ; B lds row = nh*128 + wn*32 + q.
#define LDA(buf_, mh_) do {                                                    \
    const uint16_t* Ab_ = As_ + (buf_) * TILE_E + (mh_) * 8192;                \
    _Pragma("unroll")                                                          \
    for (int mi = 0; mi < 4; ++mi) {                                           \
        int r_ = wm * 64 + mi * 16 + ml;                                       \
        int rr_ = (mh_) * 128 + r_;                                            \
        af[mi][0] = *(const bf16x8*)&Ab_[r_ * BK + (((kg)     ^ (rr_ & 7)) * 8)]; \
        af[mi][1] = *(const bf16x8*)&Ab_[r_ * BK + (((4 + kg) ^ (rr_ & 7)) * 8)]; \
    }                                                                          \
} while (0)

#define LDB(buf_, nh_) do {                                                    \
    const uint16_t* Bb_ = Bs_ + (buf_) * TILE_E + (nh_) * 8192;                \
    _Pragma("unroll")                                                          \
    for (int ni = 0; ni < 2; ++ni) {                                           \
        int r_ = wn * 32 + ni * 16 + ml;                                       \
        int rr_ = (nh_) * 128 + r_;                                            \
        bfr[ni][0] = *(const bf16x8*)&Bb_[r_ * BK + (((kg)     ^ (rr_ & 7)) * 8)]; \
        bfr[ni][1] = *(const bf16x8*)&Bb_[r_ * BK + (((4 + kg) ^ (rr_ & 7)) * 8)]; \
    }                                                                          \
} while (0)

#define MMA(mh_, nh_) do {                                                     \
    __builtin_amdgcn_s_setprio(1);                                             \
    _Pragma("unroll")                                                          \
    for (int h2 = 0; h2 < 2; ++h2)                                             \
        _Pragma("unroll")                                                      \
        for (int mi = 0; mi < 4; ++mi)                                         \
            _Pragma("unroll")                                                  \
            for (int ni = 0; ni < 2; ++ni)                                     \
                acc[(mh_) * 4 + mi][(nh_) * 2 + ni] =                          \
                    __builtin_amdgcn_mfma_f32_16x16x32_bf16(                   \
                        af[mi][h2], bfr[ni][h2],                               \
                        acc[(mh_) * 4 + mi][(nh_) * 2 + ni], 0, 0, 0);         \
    __builtin_amdgcn_s_setprio(0);                                             \
} while (0)

// One K-tile = 4 phases, m-major quadrants. No explicit lgkm drains: the
// compiler inserts fine-grained lgkmcnt before each MFMA's operand use.
#define DO_KTILE(BUF, KT_B, GB, KT_A, GA, VM6)                                 \
    /* p0: (m0,n0) */                                                          \
    LDA(BUF, 0); LDB(BUF, 0);                                                  \
    if (GB) STAGE_B(1 - (BUF), 0, KT_B);                                       \
    BAR();                                                                     \
    MMA(0, 0);                                                                 \
    BAR();                                                                     \
    /* p1: (m0,n1) */                                                          \
    LDB(BUF, 1);                                                               \
    if (GA) STAGE_A(BUF, 0, KT_A);                                             \
    BAR();                                                                     \
    MMA(0, 1);                                                                 \
    BAR();                                                                     \
    /* p2: (m1,n1) */                                                          \
    LDA(BUF, 1);                                                               \
    if (GA) STAGE_B(BUF, 1, KT_A);                                             \
    BAR();                                                                     \
    MMA(1, 1);                                                                 \
    BAR();                                                                     \
    /* p3: (m1,n0) */                                                          \
    LDB(BUF, 0);                                                               \
    if (GA) STAGE_A(BUF, 1, KT_A);                                             \
    BAR();                                                                     \
    MMA(1, 0);                                                                 \
    if (VM6) { asm volatile("s_waitcnt vmcnt(6)" ::: "memory"); }              \
    else     { asm volatile("s_waitcnt vmcnt(0)" ::: "memory"); }              \
    SB();                                                                      \
    BAR();

__global__ void __launch_bounds__(512, 2)
tdnn_gemm(const uint16_t* __restrict__ xb,
          const uint16_t* __restrict__ wb,
          const float* __restrict__ bias,
          float* __restrict__ out) {
    __shared__ uint16_t As_[2 * TILE_E];   // 64 KB (double-buffered A)
    __shared__ uint16_t Bs_[2 * TILE_E];   // 64 KB (double-buffered B)

    // XCD-aware swizzle: 256 blocks, 32/XCD; the 2 N-tiles of one M-tile are
    // adjacent on the same XCD (A-panel L2 reuse).
    const int j  = blockIdx.x;             // 0..255
    const int g  = (j & 7) * 32 + (j >> 3);
    const int mt = g >> 1;                 // 0..127
    const int nt = g & 1;
    const int b  = mt >> 2;
    const int t0 = (mt & 3) * BM;
    const int n0 = nt * BN;

    const int tid  = threadIdx.x;
    const int lane = tid & 63;
    const int w    = tid >> 6;             // wave 0..7
    const int wm   = w >> 2;               // 0..1
    const int wn   = w & 3;                // 0..3
    const int ml   = lane & 15;
    const int kg   = lane >> 4;            // 16B-chunk group within K=32

    const uint16_t* xrow = xb + (size_t)b * TLEN * DIN + (size_t)t0 * DIN;
    const uint16_t* wrow = wb + (size_t)n0 * KDIM;

    f32x4 acc[8][4] = {};
    bf16x8 af[4][2];
    bf16x8 bfr[2][2];

    // Prologue: kt0 fully + kt1.{A-H0,B-H1,A-H1}; kt1.B-H0 is issued at kt0.p0.
    // vmcnt(6): 3 newest halves (kt1's) may fly, kt0's 4 halves have landed.
    STAGE_A(0, 0, 0);
    STAGE_B(0, 0, 0);
    STAGE_A(0, 1, 0);
    STAGE_B(0, 1, 0);
    STAGE_A(1, 0, 1);
    STAGE_B(1, 1, 1);
    STAGE_A(1, 1, 1);
    asm volatile("s_waitcnt vmcnt(6)" ::: "memory");
    SB();
    BAR();

    for (int kt = 0; kt < NT; kt += 2) {
        const bool ga0 = (kt + 2) < NT;
        const bool ga1 = (kt + 3) < NT;
        DO_KTILE(0, kt + 1, true, kt + 2, ga0, ga0)
        DO_KTILE(1, kt + 2, ga0,  kt + 3, ga1, ga1)
    }

    // Epilogue. D map: col=lane&15 -> o, row=(lane>>4)*4+r -> t (contig in t,
    // so float4 stores; tbase%4==0 always, and the t>=1020 tail is a whole
    // skipped float4 since 1020%4==0).
    const int rq = (lane >> 4) * 4;
    #pragma unroll
    for (int nf = 0; nf < 4; ++nf) {
        const int o = n0 + wn * 64 + (nf >> 1) * 32 + (nf & 1) * 16 + ml;
        const float bv = bias[o];
        float* orow = out + ((size_t)b * DOUT + o) * TOUT;
        #pragma unroll
        for (int mf = 0; mf < 8; ++mf) {
            const int tb_ = t0 + wm * 128 + (mf >> 2) * 64 + (mf & 3) * 16 + rq;
            if (tb_ + 3 < TOUT) {
                float4 s;
                s.x = fmaxf(acc[mf][nf][0] + bv, 0.0f);
                s.y = fmaxf(acc[mf][nf][1] + bv, 0.0f);
                s.z = fmaxf(acc[mf][nf][2] + bv, 0.0f);
                s.w = fmaxf(acc[mf][nf][3] + bv, 0.0f);
                *(float4*)(orow + tb_) = s;
            }
        }
    }
}

extern "C" void kernel_launch(void* const* d_in, const int* in_sizes, int n_in,
                              void* d_out, int out_size, void* d_ws, size_t ws_size,
                              hipStream_t stream) {
    const float* x    = (const float*)d_in[0];
    const float* wgt  = (const float*)d_in[1];
    const float* bias = (const float*)d_in[2];
    float* out = (float*)d_out;

    // ws layout: xb first (b=31 im2col tail over-read lands in wb, not OOB)
    uint16_t* xb = (uint16_t*)d_ws;                                   // 33.55 MB
    uint16_t* wb = (uint16_t*)((char*)d_ws + (size_t)BATCH * TLEN * DIN * 2);

    convert_pack<<<1024, 256, 0, stream>>>((const float4*)x, (uint4*)xb, wgt, wb);
    tdnn_gemm<<<256, 512, 0, stream>>>(xb, wb, bias, out);
}

// Round 7
// 195.513 us; speedup vs baseline: 1.2594x; 1.0148x over previous
//
#include <hip/hip_runtime.h>
#include <stdint.h>

#define BATCH 32
#define TLEN  1024
#define DIN   512
#define DOUT  512
#define KW    5
#define TOUT  1020          // TLEN - KW + 1
#define KDIM  (DIN * KW)    // 2560

#define BM 256
#define BN 256
#define BK 64
#define NT (KDIM / BK)      // 40 K-tiles
#define TILE_E (BM * BK)    // 16384 bf16 elems per buffer per matrix (32 KB)

typedef __attribute__((ext_vector_type(8))) short bf16x8;
typedef __attribute__((ext_vector_type(4))) float f32x4;

__device__ __forceinline__ uint16_t f2bf(float f) {
    uint32_t u = __float_as_uint(f);
    uint32_t r = u + 0x7FFFu + ((u >> 16) & 1u);   // RNE to bf16
    return (uint16_t)(r >> 16);
}

// Grid-strided fat-block convert+pack.
__global__ void __launch_bounds__(256)
convert_pack(const float4* __restrict__ x, uint4* __restrict__ xb,
             const float* __restrict__ w, uint16_t* __restrict__ wb) {
    const int tid = threadIdx.x;
    for (int u = blockIdx.x; u < 8192; u += 1024) {
        int idx = u * 256 + tid;
        float4 a = x[2 * idx];
        float4 b = x[2 * idx + 1];
        uint4 v;
        v.x = (uint32_t)f2bf(a.x) | ((uint32_t)f2bf(a.y) << 16);
        v.y = (uint32_t)f2bf(a.z) | ((uint32_t)f2bf(a.w) << 16);
        v.z = (uint32_t)f2bf(b.x) | ((uint32_t)f2bf(b.y) << 16);
        v.w = (uint32_t)f2bf(b.z) | ((uint32_t)f2bf(b.w) << 16);
        xb[idx] = v;
    }
    __shared__ float4 lw4[320];
    float* lw = (float*)lw4;
    const int o = blockIdx.x >> 1;
    const int h = blockIdx.x & 1;
    const float4* src = (const float4*)(w + (size_t)o * KDIM + h * 1280);
    #pragma unroll
    for (int j = tid; j < 320; j += 256) lw4[j] = src[j];
    __syncthreads();
    #pragma unroll
    for (int k = 0; k < KW; ++k)
        wb[(size_t)o * KDIM + k * DIN + h * 256 + tid] = f2bf(lw[tid * 5 + k]);
}

// ---------------------------------------------------------------------------
// GEMM: C[m=(b,t), n=o] = sum_k xflat[b, t*512+k] * Wb[n][k]   (im2col view)
//
// One barrier per phase; WAR safety restored via COMPLETION-based ordering
// (fix of the round-5 race): each phase is
//     STAGE(future) ; ds_reads(p) ; s_waitcnt lgkmcnt(0) ; s_barrier ; MFMA(p)
// The pre-barrier lgkm drain means every wave's phase-p ds_reads are SERVICED
// before it enters BAR_p, so a stage issued at p+1 (after BAR_p) cannot have
// its DMA write land before a still-queued read (cross-wave LDS/DMA order is
// NOT FIFO — m152 class).  Overlap is preserved: a wave leaving MFMA(p) flows
// into p+1's stages/reads/drain while slower waves still MFMA.
//
// Ledger (identical vm issue order to verified round-2/4):
//  WAR: STAGE_B(kt+1,B-H0,buf^1)@p0 vs readers kt-1.p3: drained+BAR'_p3. OK
//       STAGE_A(kt+2,A-H0)@p1 vs LDA(BUF,0)@p0: drained+BAR_p0. OK
//       STAGE_B(kt+2,B-H1)@p2 vs LDB(BUF,1)@p1: drained+BAR_p1. OK
//       STAGE_A(kt+2,A-H1)@p3 vs LDA(BUF,1)@p2: drained+BAR_p2. OK
//  RAW: at kt.p3, outstanding vm ops newest-first = A-H1(kt+2) 2, B-H1(kt+2)
//       2, A-H0(kt+2) 2, B-H0(kt+1) 2, ...  vmcnt(6) forces completion of
//       B-H0(kt+1) and all older (= all kt+1 regions), then tile-end barrier;
//       all reads of kt+1 are after it. OK
//  Barriers: 5/K-tile, all wave-uniform (GB/GA guard stage issues only).
// ---------------------------------------------------------------------------

#define SB() __builtin_amdgcn_sched_barrier(0)
#define BAR() __builtin_amdgcn_s_barrier()
#define DRAINLG() asm volatile("s_waitcnt lgkmcnt(0)" ::: "memory")

#define STAGE_A(buf_, mh_, kt_) do {                                           \
    _Pragma("unroll")                                                          \
    for (int ii = 0; ii < 2; ++ii) {                                          \
        int c_  = ii * 512 + w * 64 + lane;                                   \
        int rh_ = c_ >> 3;                                                    \
        int g_  = (c_ & 7) ^ (rh_ & 7);                                       \
        int gr_ = ((rh_ >> 6) << 7) + (mh_) * 64 + (rh_ & 63);                \
        const uint16_t* gp_ = xrow + (size_t)gr_ * DIN + (kt_) * BK + g_ * 8; \
        const uint16_t* lp_ = As_ + (buf_) * TILE_E + (mh_) * 8192 + (ii * 512 + w * 64) * 8; \
        __builtin_amdgcn_global_load_lds(                                     \
            (const __attribute__((address_space(1))) void*)gp_,               \
            (__attribute__((address_space(3))) void*)lp_, 16, 0, 0);          \
    }                                                                          \
} while (0)

#define STAGE_B(buf_, nh_, kt_) do {                                           \
    _Pragma("unroll")                                                          \
    for (int ii = 0; ii < 2; ++ii) {                                          \
        int c_  = ii * 512 + w * 64 + lane;                                   \
        int rh_ = c_ >> 3;                                                    \
        int g_  = (c_ & 7) ^ (rh_ & 7);                                       \
        int gr_ = ((rh_ >> 5) << 6) + (nh_) * 32 + (rh_ & 31);                \
        const uint16_t* gp_ = wrow + (size_t)gr_ * KDIM + (kt_) * BK + g_ * 8;\
        const uint16_t* lp_ = Bs_ + (buf_) * TILE_E + (nh_) * 8192 + (ii * 512 + w * 64) * 8; \
        __builtin_amdgcn_global_load_lds(                                     \
            (const __attribute__((address_space(1))) void*)gp_,               \
            (__attribute__((address_space(3))) void*)lp_, 16, 0, 0);          \
    }                                                                          \
} while (0)

// A lds row = mh*128 + wm*64 + q ; B lds row = nh*128 + wn*32 + q.
#define LDA(buf_, mh_) do {                                                    \
    const uint16_t* Ab_ = As_ + (buf_) * TILE_E + (mh_) * 8192;                \
    _Pragma("unroll")                                                          \
    for (int mi = 0; mi < 4; ++mi) {                                           \
        int r_ = wm * 64 + mi * 16 + ml;                                       \
        int rr_ = (mh_) * 128 + r_;                                            \
        af[mi][0] = *(const bf16x8*)&Ab_[r_ * BK + (((kg)     ^ (rr_ & 7)) * 8)]; \
        af[mi][1] = *(const bf16x8*)&Ab_[r_ * BK + (((4 + kg) ^ (rr_ & 7)) * 8)]; \
    }                                                                          \
} while (0)

#define LDB(buf_, nh_) do {                                                    \
    const uint16_t* Bb_ = Bs_ + (buf_) * TILE_E + (nh_) * 8192;                \
    _Pragma("unroll")                                                          \
    for (int ni = 0; ni < 2; ++ni) {                                           \
        int r_ = wn * 32 + ni * 16 + ml;                                       \
        int rr_ = (nh_) * 128 + r_;                                            \
        bfr[ni][0] = *(const bf16x8*)&Bb_[r_ * BK + (((kg)     ^ (rr_ & 7)) * 8)]; \
        bfr[ni][1] = *(const bf16x8*)&Bb_[r_ * BK + (((4 + kg) ^ (rr_ & 7)) * 8)]; \
    }                                                                          \
} while (0)

#define MMA(mh_, nh_) do {                                                     \
    __builtin_amdgcn_s_setprio(1);                                             \
    _Pragma("unroll")                                                          \
    for (int h2 = 0; h2 < 2; ++h2)                                             \
        _Pragma("unroll")                                                      \
        for (int mi = 0; mi < 4; ++mi)                                         \
            _Pragma("unroll")                                                  \
            for (int ni = 0; ni < 2; ++ni)                                     \
                acc[(mh_) * 4 + mi][(nh_) * 2 + ni] =                          \
                    __builtin_amdgcn_mfma_f32_16x16x32_bf16(                   \
                        af[mi][h2], bfr[ni][h2],                               \
                        acc[(mh_) * 4 + mi][(nh_) * 2 + ni], 0, 0, 0);         \
    __builtin_amdgcn_s_setprio(0);                                             \
} while (0)

// One K-tile = 4 phases {stage; reads; drain; barrier; MMA} + tile-end
// counted-vmcnt barrier.
#define DO_KTILE(BUF, KT_B, GB, KT_A, GA, VM6)                                 \
    /* p0: (m0,n0) */                                                          \
    if (GB) STAGE_B(1 - (BUF), 0, KT_B);                                       \
    LDA(BUF, 0); LDB(BUF, 0);                                                  \
    DRAINLG(); BAR(); SB();                                                    \
    MMA(0, 0);                                                                 \
    /* p1: (m0,n1) */                                                          \
    if (GA) STAGE_A(BUF, 0, KT_A);                                             \
    LDB(BUF, 1);                                                               \
    DRAINLG(); BAR(); SB();                                                    \
    MMA(0, 1);                                                                 \
    /* p2: (m1,n1) */                                                          \
    if (GA) STAGE_B(BUF, 1, KT_A);                                             \
    LDA(BUF, 1);                                                               \
    DRAINLG(); BAR(); SB();                                                    \
    MMA(1, 1);                                                                 \
    /* p3: (m1,n0) */                                                          \
    if (GA) STAGE_A(BUF, 1, KT_A);                                             \
    LDB(BUF, 0);                                                               \
    DRAINLG(); BAR(); SB();                                                    \
    MMA(1, 0);                                                                 \
    if (VM6) { asm volatile("s_waitcnt vmcnt(6)" ::: "memory"); }              \
    else     { asm volatile("s_waitcnt vmcnt(0)" ::: "memory"); }              \
    SB();                                                                      \
    BAR();                                                                     \
    SB();

__global__ void __launch_bounds__(512, 2)
tdnn_gemm(const uint16_t* __restrict__ xb,
          const uint16_t* __restrict__ wb,
          const float* __restrict__ bias,
          float* __restrict__ out) {
    __shared__ uint16_t As_[2 * TILE_E];   // 64 KB (double-buffered A)
    __shared__ uint16_t Bs_[2 * TILE_E];   // 64 KB (double-buffered B)

    // XCD-aware swizzle: 256 blocks, 32/XCD; the 2 N-tiles of one M-tile are
    // adjacent on the same XCD (A-panel L2 reuse).
    const int j  = blockIdx.x;             // 0..255
    const int g  = (j & 7) * 32 + (j >> 3);
    const int mt = g >> 1;                 // 0..127
    const int nt = g & 1;
    const int b  = mt >> 2;
    const int t0 = (mt & 3) * BM;
    const int n0 = nt * BN;

    const int tid  = threadIdx.x;
    const int lane = tid & 63;
    const int w    = tid >> 6;             // wave 0..7
    const int wm   = w >> 2;               // 0..1
    const int wn   = w & 3;                // 0..3
    const int ml   = lane & 15;
    const int kg   = lane >> 4;            // 16B-chunk group within K=32

    const uint16_t* xrow = xb + (size_t)b * TLEN * DIN + (size_t)t0 * DIN;
    const uint16_t* wrow = wb + (size_t)n0 * KDIM;

    f32x4 acc[8][4] = {};
    bf16x8 af[4][2];
    bf16x8 bfr[2][2];

    // Prologue: kt0 fully + kt1.{A-H0,B-H1,A-H1}; kt1.B-H0 is issued at kt0.p0.
    // vmcnt(6): 3 newest halves (kt1's) may fly, kt0's 4 halves have landed.
    STAGE_A(0, 0, 0);
    STAGE_B(0, 0, 0);
    STAGE_A(0, 1, 0);
    STAGE_B(0, 1, 0);
    STAGE_A(1, 0, 1);
    STAGE_B(1, 1, 1);
    STAGE_A(1, 1, 1);
    asm volatile("s_waitcnt vmcnt(6)" ::: "memory");
    SB();
    BAR();
    SB();

    for (int kt = 0; kt < NT; kt += 2) {
        const bool ga0 = (kt + 2) < NT;
        const bool ga1 = (kt + 3) < NT;
        DO_KTILE(0, kt + 1, true, kt + 2, ga0, ga0)
        DO_KTILE(1, kt + 2, ga0,  kt + 3, ga1, ga1)
    }

    // Epilogue. D map: col=lane&15 -> o, row=(lane>>4)*4+r -> t (contig in t,
    // so float4 stores; tbase%4==0 always, and the t>=1020 tail is a whole
    // skipped float4 since 1020%4==0).
    const int rq = (lane >> 4) * 4;
    #pragma unroll
    for (int nf = 0; nf < 4; ++nf) {
        const int o = n0 + wn * 64 + (nf >> 1) * 32 + (nf & 1) * 16 + ml;
        const float bv = bias[o];
        float* orow = out + ((size_t)b * DOUT + o) * TOUT;
        #pragma unroll
        for (int mf = 0; mf < 8; ++mf) {
            const int tb_ = t0 + wm * 128 + (mf >> 2) * 64 + (mf & 3) * 16 + rq;
            if (tb_ + 3 < TOUT) {
                float4 s;
                s.x = fmaxf(acc[mf][nf][0] + bv, 0.0f);
                s.y = fmaxf(acc[mf][nf][1] + bv, 0.0f);
                s.z = fmaxf(acc[mf][nf][2] + bv, 0.0f);
                s.w = fmaxf(acc[mf][nf][3] + bv, 0.0f);
                *(float4*)(orow + tb_) = s;
            }
        }
    }
}

extern "C" void kernel_launch(void* const* d_in, const int* in_sizes, int n_in,
                              void* d_out, int out_size, void* d_ws, size_t ws_size,
                              hipStream_t stream) {
    const float* x    = (const float*)d_in[0];
    const float* wgt  = (const float*)d_in[1];
    const float* bias = (const float*)d_in[2];
    float* out = (float*)d_out;

    // ws layout: xb first (b=31 im2col tail over-read lands in wb, not OOB)
    uint16_t* xb = (uint16_t*)d_ws;                                   // 33.55 MB
    uint16_t* wb = (uint16_t*)((char*)d_ws + (size_t)BATCH * TLEN * DIN * 2);

    convert_pack<<<1024, 256, 0, stream>>>((const float4*)x, (uint4*)xb, wgt, wb);
    tdnn_gemm<<<256, 512, 0, stream>>>(xb, wb, bias, out);
}

// Round 8
// 195.053 us; speedup vs baseline: 1.2624x; 1.0024x over previous
//
#include <hip/hip_runtime.h>
#include <stdint.h>

#define BATCH 32
#define TLEN  1024
#define DIN   512
#define DOUT  512
#define KW    5
#define TOUT  1020          // TLEN - KW + 1
#define KDIM  (DIN * KW)    // 2560

#define BM 256
#define BN 256
#define BK 64
#define NT (KDIM / BK)      // 40 K-tiles
#define TILE_E (BM * BK)    // 16384 bf16 elems per buffer per matrix (32 KB)

typedef __attribute__((ext_vector_type(8))) short bf16x8;
typedef __attribute__((ext_vector_type(4))) float f32x4;

__device__ __forceinline__ uint16_t f2bf(float f) {
    uint32_t u = __float_as_uint(f);
    uint32_t r = u + 0x7FFFu + ((u >> 16) & 1u);   // RNE to bf16
    return (uint16_t)(r >> 16);
}

// Grid-strided fat-block convert+pack.
__global__ void __launch_bounds__(256)
convert_pack(const float4* __restrict__ x, uint4* __restrict__ xb,
             const float* __restrict__ w, uint16_t* __restrict__ wb) {
    const int tid = threadIdx.x;
    for (int u = blockIdx.x; u < 8192; u += 1024) {
        int idx = u * 256 + tid;
        float4 a = x[2 * idx];
        float4 b = x[2 * idx + 1];
        uint4 v;
        v.x = (uint32_t)f2bf(a.x) | ((uint32_t)f2bf(a.y) << 16);
        v.y = (uint32_t)f2bf(a.z) | ((uint32_t)f2bf(a.w) << 16);
        v.z = (uint32_t)f2bf(b.x) | ((uint32_t)f2bf(b.y) << 16);
        v.w = (uint32_t)f2bf(b.z) | ((uint32_t)f2bf(b.w) << 16);
        xb[idx] = v;
    }
    __shared__ float4 lw4[320];
    float* lw = (float*)lw4;
    const int o = blockIdx.x >> 1;
    const int h = blockIdx.x & 1;
    const float4* src = (const float4*)(w + (size_t)o * KDIM + h * 1280);
    #pragma unroll
    for (int j = tid; j < 320; j += 256) lw4[j] = src[j];
    __syncthreads();
    #pragma unroll
    for (int k = 0; k < KW; ++k)
        wb[(size_t)o * KDIM + k * DIN + h * 256 + tid] = f2bf(lw[tid * 5 + k]);
}

// ---------------------------------------------------------------------------
// GEMM: C[m=(b,t), n=o] = sum_k xflat[b, t*512+k] * Wb[n][k]   (im2col view)
//
// WAR-stall reduction (round-8): measured 1425 cyc/phase == full serial sum;
// cause is register WAR: each phase's ds_reads overwrite the fragment regs
// the PREVIOUS MFMA cluster still reads (distance-0) -> reads stall until the
// cluster drains. Fix within the 256-reg budget: B fragments become two
// persistent sets (bf0 = B-H0, bf1 = B-H1, no re-read) and the cluster order
// changes to B-ALTERNATING:  p0 (m0,n0) af·bf0 ; p1 (m0,n1) af·bf1 ;
//                            p2 (m1,n0) af·bf0 ; p3 (m1,n1) af·bf1.
// Rewrite distances: bf0@kt+1.p0 after last use kt.p2 -> 1 full cluster
// window (drained) OK; bf1@kt+1.p1 after last use kt.p3 -> 1 window OK.
// af stays shared (H0@p0, H1@p2) -> 2 remaining distance-0 stalls (fixing
// them needs +32 VGPR we don't have).
//
// Phase = { STAGE(future) ; ds_reads ; lgkmcnt(0) ; s_barrier ; MFMA } —
// completion-based WAR ordering for LDS staging (round-7 ledger, verified):
//  - stage at phase p+1 lands after BAR_p, entered only after every wave's
//    phase-p reads were SERVICED (pre-barrier lgkm drain).
//    B-H0(kt+1)->buf^1 @p0: buf^1 B-H0 readers kt-1.p0, long drained. OK
//    A-H0(kt+2)@p1 vs LDA(BUF,0)@p0: drained at BAR_p0. OK
//    B-H1(kt+2)@p2 vs LDB1(BUF)@p1: drained at BAR_p1. OK
//    A-H1(kt+2)@p3 vs LDA(BUF,1)@p2: drained at BAR_p2. OK
//  - RAW: at kt.p3 vmcnt(6) leaves only kt+2's 6 stage-loads in flight ->
//    proves all of kt+1's halves + kt+1.B-H0 before the tile-end barrier;
//    all reads of kt+1 follow it. OK (identical vm issue order to rounds 2-7)
//  - Barriers wave-uniform (GB/GA guard stage issues only).
// ---------------------------------------------------------------------------

#define SB() __builtin_amdgcn_sched_barrier(0)
#define BAR() __builtin_amdgcn_s_barrier()
#define DRAINLG() asm volatile("s_waitcnt lgkmcnt(0)" ::: "memory")

#define STAGE_A(buf_, mh_, kt_) do {                                           \
    _Pragma("unroll")                                                          \
    for (int ii = 0; ii < 2; ++ii) {                                          \
        int c_  = ii * 512 + w * 64 + lane;                                   \
        int rh_ = c_ >> 3;                                                    \
        int g_  = (c_ & 7) ^ (rh_ & 7);                                       \
        int gr_ = ((rh_ >> 6) << 7) + (mh_) * 64 + (rh_ & 63);                \
        const uint16_t* gp_ = xrow + (size_t)gr_ * DIN + (kt_) * BK + g_ * 8; \
        const uint16_t* lp_ = As_ + (buf_) * TILE_E + (mh_) * 8192 + (ii * 512 + w * 64) * 8; \
        __builtin_amdgcn_global_load_lds(                                     \
            (const __attribute__((address_space(1))) void*)gp_,               \
            (__attribute__((address_space(3))) void*)lp_, 16, 0, 0);          \
    }                                                                          \
} while (0)

#define STAGE_B(buf_, nh_, kt_) do {                                           \
    _Pragma("unroll")                                                          \
    for (int ii = 0; ii < 2; ++ii) {                                          \
        int c_  = ii * 512 + w * 64 + lane;                                   \
        int rh_ = c_ >> 3;                                                    \
        int g_  = (c_ & 7) ^ (rh_ & 7);                                       \
        int gr_ = ((rh_ >> 5) << 6) + (nh_) * 32 + (rh_ & 31);                \
        const uint16_t* gp_ = wrow + (size_t)gr_ * KDIM + (kt_) * BK + g_ * 8;\
        const uint16_t* lp_ = Bs_ + (buf_) * TILE_E + (nh_) * 8192 + (ii * 512 + w * 64) * 8; \
        __builtin_amdgcn_global_load_lds(                                     \
            (const __attribute__((address_space(1))) void*)gp_,               \
            (__attribute__((address_space(3))) void*)lp_, 16, 0, 0);          \
    }                                                                          \
} while (0)

// A lds row = mh*128 + wm*64 + q ; B lds row = nh*128 + wn*32 + q.
#define LDA(buf_, mh_) do {                                                    \
    const uint16_t* Ab_ = As_ + (buf_) * TILE_E + (mh_) * 8192;                \
    _Pragma("unroll")                                                          \
    for (int mi = 0; mi < 4; ++mi) {                                           \
        int r_ = wm * 64 + mi * 16 + ml;                                       \
        int rr_ = (mh_) * 128 + r_;                                            \
        af[mi][0] = *(const bf16x8*)&Ab_[r_ * BK + (((kg)     ^ (rr_ & 7)) * 8)]; \
        af[mi][1] = *(const bf16x8*)&Ab_[r_ * BK + (((4 + kg) ^ (rr_ & 7)) * 8)]; \
    }                                                                          \
} while (0)

#define LDB0(buf_) do {                                                        \
    const uint16_t* Bb_ = Bs_ + (buf_) * TILE_E;                               \
    _Pragma("unroll")                                                          \
    for (int ni = 0; ni < 2; ++ni) {                                           \
        int r_ = wn * 32 + ni * 16 + ml;                                       \
        bf0[ni][0] = *(const bf16x8*)&Bb_[r_ * BK + (((kg)     ^ (r_ & 7)) * 8)]; \
        bf0[ni][1] = *(const bf16x8*)&Bb_[r_ * BK + (((4 + kg) ^ (r_ & 7)) * 8)]; \
    }                                                                          \
} while (0)

#define LDB1(buf_) do {                                                        \
    const uint16_t* Bb_ = Bs_ + (buf_) * TILE_E + 8192;                        \
    _Pragma("unroll")                                                          \
    for (int ni = 0; ni < 2; ++ni) {                                           \
        int r_ = wn * 32 + ni * 16 + ml;                                       \
        int rr_ = 128 + r_;                                                    \
        bf1[ni][0] = *(const bf16x8*)&Bb_[r_ * BK + (((kg)     ^ (rr_ & 7)) * 8)]; \
        bf1[ni][1] = *(const bf16x8*)&Bb_[r_ * BK + (((4 + kg) ^ (rr_ & 7)) * 8)]; \
    }                                                                          \
} while (0)

#define MMA(mh_, nh_, BF_) do {                                                \
    __builtin_amdgcn_s_setprio(1);                                             \
    _Pragma("unroll")                                                          \
    for (int h2 = 0; h2 < 2; ++h2)                                             \
        _Pragma("unroll")                                                      \
        for (int mi = 0; mi < 4; ++mi)                                         \
            _Pragma("unroll")                                                  \
            for (int ni = 0; ni < 2; ++ni)                                     \
                acc[(mh_) * 4 + mi][(nh_) * 2 + ni] =                          \
                    __builtin_amdgcn_mfma_f32_16x16x32_bf16(                   \
                        af[mi][h2], BF_[ni][h2],                               \
                        acc[(mh_) * 4 + mi][(nh_) * 2 + ni], 0, 0, 0);         \
    __builtin_amdgcn_s_setprio(0);                                             \
} while (0)

// One K-tile = 4 phases, B-alternating cluster order; B sets persist, no
// re-read; p3 has no ds_reads. Tile-end: counted vmcnt + barrier.
#define DO_KTILE(BUF, KT_B, GB, KT_A, GA, VM6)                                 \
    /* p0: (m0,n0) af(H0)·bf0 */                                               \
    if (GB) STAGE_B(1 - (BUF), 0, KT_B);                                       \
    LDA(BUF, 0); LDB0(BUF);                                                    \
    DRAINLG(); BAR(); SB();                                                    \
    MMA(0, 0, bf0);                                                            \
    /* p1: (m0,n1) af(H0)·bf1 */                                               \
    if (GA) STAGE_A(BUF, 0, KT_A);                                             \
    LDB1(BUF);                                                                 \
    DRAINLG(); BAR(); SB();                                                    \
    MMA(0, 1, bf1);                                                            \
    /* p2: (m1,n0) af(H1)·bf0 */                                               \
    if (GA) STAGE_B(BUF, 1, KT_A);                                             \
    LDA(BUF, 1);                                                               \
    DRAINLG(); BAR(); SB();                                                    \
    MMA(1, 0, bf0);                                                            \
    /* p3: (m1,n1) af(H1)·bf1 — no reads */                                    \
    if (GA) STAGE_A(BUF, 1, KT_A);                                             \
    DRAINLG(); BAR(); SB();                                                    \
    MMA(1, 1, bf1);                                                            \
    if (VM6) { asm volatile("s_waitcnt vmcnt(6)" ::: "memory"); }              \
    else     { asm volatile("s_waitcnt vmcnt(0)" ::: "memory"); }              \
    SB();                                                                      \
    BAR();                                                                     \
    SB();

__global__ void __launch_bounds__(512, 2)
tdnn_gemm(const uint16_t* __restrict__ xb,
          const uint16_t* __restrict__ wb,
          const float* __restrict__ bias,
          float* __restrict__ out) {
    __shared__ uint16_t As_[2 * TILE_E];   // 64 KB (double-buffered A)
    __shared__ uint16_t Bs_[2 * TILE_E];   // 64 KB (double-buffered B)

    // XCD-aware swizzle: 256 blocks, 32/XCD; the 2 N-tiles of one M-tile are
    // adjacent on the same XCD (A-panel L2 reuse).
    const int j  = blockIdx.x;             // 0..255
    const int g  = (j & 7) * 32 + (j >> 3);
    const int mt = g >> 1;                 // 0..127
    const int nt = g & 1;
    const int b  = mt >> 2;
    const int t0 = (mt & 3) * BM;
    const int n0 = nt * BN;

    const int tid  = threadIdx.x;
    const int lane = tid & 63;
    const int w    = tid >> 6;             // wave 0..7
    const int wm   = w >> 2;               // 0..1
    const int wn   = w & 3;                // 0..3
    const int ml   = lane & 15;
    const int kg   = lane >> 4;            // 16B-chunk group within K=32

    const uint16_t* xrow = xb + (size_t)b * TLEN * DIN + (size_t)t0 * DIN;
    const uint16_t* wrow = wb + (size_t)n0 * KDIM;

    f32x4 acc[8][4] = {};
    bf16x8 af[4][2];
    bf16x8 bf0[2][2];
    bf16x8 bf1[2][2];

    // Prologue: kt0 fully + kt1.{A-H0,B-H1,A-H1}; kt1.B-H0 is issued at kt0.p0.
    // vmcnt(6): 3 newest halves (kt1's) may fly, kt0's 4 halves have landed.
    STAGE_A(0, 0, 0);
    STAGE_B(0, 0, 0);
    STAGE_A(0, 1, 0);
    STAGE_B(0, 1, 0);
    STAGE_A(1, 0, 1);
    STAGE_B(1, 1, 1);
    STAGE_A(1, 1, 1);
    asm volatile("s_waitcnt vmcnt(6)" ::: "memory");
    SB();
    BAR();
    SB();

    for (int kt = 0; kt < NT; kt += 2) {
        const bool ga0 = (kt + 2) < NT;
        const bool ga1 = (kt + 3) < NT;
        DO_KTILE(0, kt + 1, true, kt + 2, ga0, ga0)
        DO_KTILE(1, kt + 2, ga0,  kt + 3, ga1, ga1)
    }

    // Epilogue. D map: col=lane&15 -> o, row=(lane>>4)*4+r -> t (contig in t,
    // so float4 stores; tbase%4==0 always, and the t>=1020 tail is a whole
    // skipped float4 since 1020%4==0).
    const int rq = (lane >> 4) * 4;
    #pragma unroll
    for (int nf = 0; nf < 4; ++nf) {
        const int o = n0 + wn * 64 + (nf >> 1) * 32 + (nf & 1) * 16 + ml;
        const float bv = bias[o];
        float* orow = out + ((size_t)b * DOUT + o) * TOUT;
        #pragma unroll
        for (int mf = 0; mf < 8; ++mf) {
            const int tb_ = t0 + wm * 128 + (mf >> 2) * 64 + (mf & 3) * 16 + rq;
            if (tb_ + 3 < TOUT) {
                float4 s;
                s.x = fmaxf(acc[mf][nf][0] + bv, 0.0f);
                s.y = fmaxf(acc[mf][nf][1] + bv, 0.0f);
                s.z = fmaxf(acc[mf][nf][2] + bv, 0.0f);
                s.w = fmaxf(acc[mf][nf][3] + bv, 0.0f);
                *(float4*)(orow + tb_) = s;
            }
        }
    }
}

extern "C" void kernel_launch(void* const* d_in, const int* in_sizes, int n_in,
                              void* d_out, int out_size, void* d_ws, size_t ws_size,
                              hipStream_t stream) {
    const float* x    = (const float*)d_in[0];
    const float* wgt  = (const float*)d_in[1];
    const float* bias = (const float*)d_in[2];
    float* out = (float*)d_out;

    // ws layout: xb first (b=31 im2col tail over-read lands in wb, not OOB)
    uint16_t* xb = (uint16_t*)d_ws;                                   // 33.55 MB
    uint16_t* wb = (uint16_t*)((char*)d_ws + (size_t)BATCH * TLEN * DIN * 2);

    convert_pack<<<1024, 256, 0, stream>>>((const float4*)x, (uint4*)xb, wgt, wb);
    tdnn_gemm<<<256, 512, 0, stream>>>(xb, wb, bias, out);
}